// Round 1
// baseline (159.631 us; speedup 1.0000x reference)
//
#include <hip/hip_runtime.h>
#include <stdint.h>

#define BATCH 32768
#define DIM   512
#define KCLS  512

typedef __bf16    bf16x8 __attribute__((ext_vector_type(8)));
typedef float     f32x4  __attribute__((ext_vector_type(4)));
typedef uint16_t  u16x4  __attribute__((ext_vector_type(4)));
typedef uint16_t  u16x8  __attribute__((ext_vector_type(8)));

__device__ __forceinline__ uint16_t f2bf(float f) {
    // RTNE fp32 -> bf16
    uint32_t u = __float_as_uint(f);
    u += 0x7FFFu + ((u >> 16) & 1u);
    return (uint16_t)(u >> 16);
}

// ---------------------------------------------------------------------------
// Prep: means (K x D fp32) -> bf16 pre-swizzled into MFMA B-fragment order.
// B-frag for mfma_f32_16x16x32_bf16: B[k = 8*(lane>>4)+j][n = lane&15],
// i.e. lane needs means[col][k0 + 8*(lane>>4) .. +7] (8 contiguous d).
// Bsw layout: index = (((c16*16 + ch)*64) + lane)*8, col = 16*c16 + (lane&15),
// k = 32*ch + 8*(lane>>4) + j.  Also computes inv_var/alpha/beta per class.
// ---------------------------------------------------------------------------
__global__ __launch_bounds__(64) void gmm_prep(
    const float* __restrict__ means,
    const float* __restrict__ log_vars,
    const float* __restrict__ log_weights,
    uint16_t* __restrict__ Bsw,
    float* __restrict__ invv_a,
    float* __restrict__ alpha_a,
    float* __restrict__ beta_a)
{
    const int k = blockIdx.x;   // class index, 512 blocks of one wave
    const int l = threadIdx.x;  // lane 0..63, reads elements 8l..8l+7 (coalesced)

    const float* mrow = means + (size_t)k * DIM + l * 8;
    f32x4 v0 = *(const f32x4*)(mrow);
    f32x4 v1 = *(const f32x4*)(mrow + 4);

    u16x8 pk;
    pk[0] = f2bf(v0[0]); pk[1] = f2bf(v0[1]); pk[2] = f2bf(v0[2]); pk[3] = f2bf(v0[3]);
    pk[4] = f2bf(v1[0]); pk[5] = f2bf(v1[1]); pk[6] = f2bf(v1[2]); pk[7] = f2bf(v1[3]);

    // writer slot: this lane's 8 elements are k-offsets 8l..8l+7 = 32*ch + 8*hh
    const int c16 = k >> 4, r = k & 15, ch = l >> 2, hh = l & 3;
    *(u16x8*)(Bsw + ((((c16 * 16) + ch) * 64) + (hh * 16 + r)) * 8) = pk;

    float sq = v0[0]*v0[0] + v0[1]*v0[1] + v0[2]*v0[2] + v0[3]*v0[3]
             + v1[0]*v1[0] + v1[1]*v1[1] + v1[2]*v1[2] + v1[3]*v1[3];
    #pragma unroll
    for (int m = 1; m <= 32; m <<= 1) sq += __shfl_xor(sq, m);

    if (l == 0) {
        const float lv = log_vars[k];
        const float iv = __expf(-lv);
        invv_a[k]  = iv;
        alpha_a[k] = -0.5f * iv;
        // log_softmax(log_weights) minus its row-constant LSE (cancels in softmax)
        beta_a[k]  = -0.5f * (sq * iv + (float)DIM * lv) + log_weights[k];
    }
}

// ---------------------------------------------------------------------------
// Main fused kernel: 32 rows/block, full K=512 in-block -> fused softmax.
// 4 waves; wave w owns cols [128w, 128w+128): 2 row-tiles x 8 col-tiles of
// 16x16x32 bf16 MFMA (64 acc VGPRs/lane). x staged fp32->bf16 via LDS
// (stride 72 bf16 = 36 dwords -> <=2-way bank aliasing, free per m136).
// B-frags load directly from L2-resident pre-swizzled Bsw (16B/lane coalesced).
// ---------------------------------------------------------------------------
__global__ __launch_bounds__(256, 2) void gmm_main(
    const float* __restrict__ x,
    const uint16_t* __restrict__ Bsw,
    const float* __restrict__ invv_a,
    const float* __restrict__ alpha_a,
    const float* __restrict__ beta_a,
    float* __restrict__ out)
{
    __shared__ uint16_t As[32][72];   // 32 rows x 32 k (padded to 72 shorts)
    __shared__ float xsq_lds[32];
    __shared__ float pmax[4][32];
    __shared__ float psum[4][32];

    const int t    = threadIdx.x;
    const int w    = t >> 6;        // wave 0..3 -> col group
    const int lane = t & 63;
    const int r16  = lane & 15;     // fragment row (A) / col (B/C)
    const int h    = lane >> 4;     // k-group / C row-quad
    const int row0 = blockIdx.x * 32;

    // staging map: thread -> (row = t>>3, k-quad = t&7), one float4 per chunk
    const int srow = t >> 3;
    const int sp   = t & 7;

    f32x4 acc[2][8];
    #pragma unroll
    for (int rt = 0; rt < 2; ++rt)
        #pragma unroll
        for (int ct = 0; ct < 8; ++ct)
            acc[rt][ct] = (f32x4){0.f, 0.f, 0.f, 0.f};

    float xsq_priv = 0.f;
    const float* xrow = x + (size_t)(row0 + srow) * DIM + sp * 4;
    const uint16_t* bbase = Bsw + (size_t)w * 65536 + (size_t)lane * 8;

    f32x4 a_pref = *(const f32x4*)xrow;   // chunk 0 prefetch

    for (int chk = 0; chk < 16; ++chk) {
        f32x4 av = a_pref;
        if (chk < 15) a_pref = *(const f32x4*)(xrow + (chk + 1) * 32);

        xsq_priv += av[0]*av[0] + av[1]*av[1] + av[2]*av[2] + av[3]*av[3];
        u16x4 pk;
        pk[0] = f2bf(av[0]); pk[1] = f2bf(av[1]);
        pk[2] = f2bf(av[2]); pk[3] = f2bf(av[3]);

        __syncthreads();                      // prior chunk's frag reads done
        *(u16x4*)&As[srow][sp * 4] = pk;      // 8B ds_write
        __syncthreads();                      // staging visible

        bf16x8 afrag0 = *(const bf16x8*)&As[r16][8 * h];
        bf16x8 afrag1 = *(const bf16x8*)&As[16 + r16][8 * h];

        bf16x8 bfrag[8];
        #pragma unroll
        for (int ct = 0; ct < 8; ++ct)
            bfrag[ct] = *(const bf16x8*)(bbase + ct * 8192 + chk * 512);

        #pragma unroll
        for (int ct = 0; ct < 8; ++ct) {
            acc[0][ct] = __builtin_amdgcn_mfma_f32_16x16x32_bf16(afrag0, bfrag[ct], acc[0][ct], 0, 0, 0);
            acc[1][ct] = __builtin_amdgcn_mfma_f32_16x16x32_bf16(afrag1, bfrag[ct], acc[1][ct], 0, 0, 0);
        }
    }

    // ---- x_sq: 8 staging threads per row are consecutive lanes ----
    xsq_priv += __shfl_xor(xsq_priv, 1);
    xsq_priv += __shfl_xor(xsq_priv, 2);
    xsq_priv += __shfl_xor(xsq_priv, 4);
    if (sp == 0) xsq_lds[srow] = xsq_priv;
    __syncthreads();

    // ---- per-column affine params (L2-hot, broadcast-ish loads) ----
    float invv[8], alf[8], bet[8];
    #pragma unroll
    for (int ct = 0; ct < 8; ++ct) {
        const int col = 128 * w + 16 * ct + r16;
        invv[ct] = invv_a[col];
        alf[ct]  = alpha_a[col];
        bet[ct]  = beta_a[col];
    }
    float xsq[2][4];
    #pragma unroll
    for (int rt = 0; rt < 2; ++rt)
        #pragma unroll
        for (int reg = 0; reg < 4; ++reg)
            xsq[rt][reg] = xsq_lds[16 * rt + 4 * h + reg];

    // ---- logits + per-row max (C layout: col=lane&15, row=4*(lane>>4)+reg) ----
    float mr[2][4];
    #pragma unroll
    for (int rt = 0; rt < 2; ++rt) {
        #pragma unroll
        for (int reg = 0; reg < 4; ++reg) {
            float m = -1e30f;
            #pragma unroll
            for (int ct = 0; ct < 8; ++ct) {
                const float v = acc[rt][ct][reg] * invv[ct] + (alf[ct] * xsq[rt][reg] + bet[ct]);
                acc[rt][ct][reg] = v;
                m = fmaxf(m, v);
            }
            m = fmaxf(m, __shfl_xor(m, 1));
            m = fmaxf(m, __shfl_xor(m, 2));
            m = fmaxf(m, __shfl_xor(m, 4));
            m = fmaxf(m, __shfl_xor(m, 8));
            mr[rt][reg] = m;
        }
    }
    if (r16 == 0) {
        #pragma unroll
        for (int rt = 0; rt < 2; ++rt)
            #pragma unroll
            for (int reg = 0; reg < 4; ++reg)
                pmax[w][16 * rt + 4 * h + reg] = mr[rt][reg];
    }
    __syncthreads();

    // ---- exp + per-row sum ----
    float sr[2][4];
    #pragma unroll
    for (int rt = 0; rt < 2; ++rt) {
        #pragma unroll
        for (int reg = 0; reg < 4; ++reg) {
            const int rl = 16 * rt + 4 * h + reg;
            const float m = fmaxf(fmaxf(pmax[0][rl], pmax[1][rl]),
                                  fmaxf(pmax[2][rl], pmax[3][rl]));
            float s = 0.f;
            #pragma unroll
            for (int ct = 0; ct < 8; ++ct) {
                const float e = __expf(acc[rt][ct][reg] - m);
                acc[rt][ct][reg] = e;
                s += e;
            }
            s += __shfl_xor(s, 1);
            s += __shfl_xor(s, 2);
            s += __shfl_xor(s, 4);
            s += __shfl_xor(s, 8);
            sr[rt][reg] = s;
        }
    }
    if (r16 == 0) {
        #pragma unroll
        for (int rt = 0; rt < 2; ++rt)
            #pragma unroll
            for (int reg = 0; reg < 4; ++reg)
                psum[w][16 * rt + 4 * h + reg] = sr[rt][reg];
    }
    __syncthreads();

    // ---- normalize + store ----
    #pragma unroll
    for (int rt = 0; rt < 2; ++rt) {
        #pragma unroll
        for (int reg = 0; reg < 4; ++reg) {
            const int rl = 16 * rt + 4 * h + reg;
            const float tot = (psum[0][rl] + psum[1][rl]) + (psum[2][rl] + psum[3][rl]);
            const float rinv = 1.0f / tot;
            float* orow = out + (size_t)(row0 + rl) * KCLS + 128 * w + r16;
            #pragma unroll
            for (int ct = 0; ct < 8; ++ct)
                orow[16 * ct] = acc[rt][ct][reg] * rinv;
        }
    }
}

extern "C" void kernel_launch(void* const* d_in, const int* in_sizes, int n_in,
                              void* d_out, int out_size, void* d_ws, size_t ws_size,
                              hipStream_t stream) {
    (void)in_sizes; (void)n_in; (void)out_size; (void)ws_size;
    const float* x           = (const float*)d_in[0];
    const float* means       = (const float*)d_in[1];
    const float* log_vars    = (const float*)d_in[2];
    const float* log_weights = (const float*)d_in[3];
    float* out = (float*)d_out;

    // ws: [0, 512KB) swizzled bf16 means; then inv_var/alpha/beta (512 f32 each)
    uint16_t* Bsw = (uint16_t*)d_ws;
    float* invv_a  = (float*)((char*)d_ws + (512u << 10));
    float* alpha_a = invv_a + KCLS;
    float* beta_a  = alpha_a + KCLS;

    gmm_prep<<<KCLS, 64, 0, stream>>>(means, log_vars, log_weights,
                                      Bsw, invv_a, alpha_a, beta_a);
    gmm_main<<<BATCH / 32, 256, 0, stream>>>(x, Bsw, invv_a, alpha_a, beta_a, out);
}